// Round 1
// baseline (172.545 us; speedup 1.0000x reference)
//
#include <hip/hip_runtime.h>

// Problem constants (B=8, Tq=Tv=512, D=512, U=128)
constexpr int Bb = 8;
constexpr int Tq = 512;
constexpr int Tv = 512;
constexpr int Dd = 512;
constexpr int Uu = 128;
constexpr float C2LOG2E = 2.88539008177792681f;   // 2*log2(e)
constexpr float LOG2E   = 1.44269504088896341f;

// ---------------------------------------------------------------------------
// Kernel A v2: projections. 16 rows/block, 256 threads, 512 blocks.
// Each WAVE owns a d-quarter (128 d's). Each thread accumulates ALL 16 rows
// for its 2 u-columns over that d-quarter (acc[16][2]) -> 4x less redundant
// W streaming than the old 4-rows/thread layout, and 128 independent FMAs
// per 8 W loads to hide L1/L2 latency at 2 waves/SIMD.
// 4-way d-partials are combined through LDS (aliased over the x buffer).
// Outputs premultiplied by 2*log2e. kT stays u4-interleaved compact:
//   kT[b][u4][pos][comp].
// ---------------------------------------------------------------------------
__global__ __launch_bounds__(256) void proj_kernel(
    const float* __restrict__ query,
    const float* __restrict__ key,
    const float* __restrict__ Wa,
    const float* __restrict__ Ua,
    const int* __restrict__ mask,
    float* __restrict__ qf2, float* __restrict__ kT)
{
    const int R    = blockIdx.x * 16;              // 0..8191
    const bool isQ = R < Bb * Tq;
    const float* __restrict__ src = isQ ? query : key;
    const float* __restrict__ W   = isQ ? Wa : Ua;
    const int Rloc = isQ ? R : R - Bb * Tq;        // 0..4095

    __shared__ float x[16 * Dd];                   // 32 KB; later aliased as part[4][16][128]
    __shared__ int posLoc[16];
    const int t = threadIdx.x;

    {   // stage 16 rows: 2048 float4, coalesced
        const float4* __restrict__ s4 =
            reinterpret_cast<const float4*>(src + (size_t)Rloc * Dd);
        float4* x4 = reinterpret_cast<float4*>(x);
#pragma unroll
        for (int m = 0; m < 8; ++m) x4[t + 256 * m] = s4[t + 256 * m];
    }
    if (!isQ && t < 64) {                          // wave-0 ballot scan -> pos
        const int b  = Rloc >> 9;
        const int j0 = Rloc & 511;                 // 16-aligned
        int base = 0;
#pragma unroll
        for (int c = 0; c < 8; ++c) {
            const int j = c * 64 + t;
            const int v = (mask[b * 512 + j] != 0);
            const unsigned long long bits = __ballot(v);
            const int pos = base + (int)__popcll(bits & ((1ull << t) - 1ull));
            if (j >= j0 && j < j0 + 16) posLoc[j - j0] = v ? pos : -1;
            base += (int)__popcll(bits);
        }
    }
    __syncthreads();

    const int ub = t & 63;                         // u column pair (ub, ub+64)
    const int dq = t >> 6;                         // wave-owned d-quarter 0..3
    const float* __restrict__ Wq = W + (size_t)dq * 128 * Uu;
    const float* __restrict__ xq = x + dq * 128;

    float acc[16][2];
#pragma unroll
    for (int r = 0; r < 16; ++r) { acc[r][0] = 0.f; acc[r][1] = 0.f; }

#pragma unroll 2
    for (int d4 = 0; d4 < 32; ++d4) {
        const int d = d4 * 4;
        const float w0x = Wq[(d + 0) * Uu + ub], w1x = Wq[(d + 0) * Uu + ub + 64];
        const float w0y = Wq[(d + 1) * Uu + ub], w1y = Wq[(d + 1) * Uu + ub + 64];
        const float w0z = Wq[(d + 2) * Uu + ub], w1z = Wq[(d + 2) * Uu + ub + 64];
        const float w0w = Wq[(d + 3) * Uu + ub], w1w = Wq[(d + 3) * Uu + ub + 64];
#pragma unroll
        for (int r = 0; r < 16; ++r) {
            const float4 xv = *reinterpret_cast<const float4*>(xq + r * Dd + d); // LDS broadcast
            acc[r][0] = fmaf(xv.x, w0x, acc[r][0]);
            acc[r][0] = fmaf(xv.y, w0y, acc[r][0]);
            acc[r][0] = fmaf(xv.z, w0z, acc[r][0]);
            acc[r][0] = fmaf(xv.w, w0w, acc[r][0]);
            acc[r][1] = fmaf(xv.x, w1x, acc[r][1]);
            acc[r][1] = fmaf(xv.y, w1y, acc[r][1]);
            acc[r][1] = fmaf(xv.z, w1z, acc[r][1]);
            acc[r][1] = fmaf(xv.w, w1w, acc[r][1]);
        }
    }

    __syncthreads();                               // all waves done reading x
    {
        float* __restrict__ part = x;              // part[dq][r][u] = ((dq*16+r)*128+u)
#pragma unroll
        for (int r = 0; r < 16; ++r) {             // stride-1 across lanes: conflict-free
            part[(dq * 16 + r) * 128 + ub]      = acc[r][0];
            part[(dq * 16 + r) * 128 + ub + 64] = acc[r][1];
        }
    }
    __syncthreads();

    // reduce the 4 d-partials and store. thread -> row r = t>>4, u0 = (t&15)*8
    {
        const float* __restrict__ part = x;
        const int r  = t >> 4;
        const int u0 = (t & 15) * 8;
        float v[8];
#pragma unroll
        for (int q = 0; q < 8; ++q) {
            const float s = part[(0 * 16 + r) * 128 + u0 + q]
                          + part[(1 * 16 + r) * 128 + u0 + q]
                          + part[(2 * 16 + r) * 128 + u0 + q]
                          + part[(3 * 16 + r) * 128 + u0 + q];
            v[q] = C2LOG2E * s;
        }
        if (isQ) {
            float4* __restrict__ dst =
                reinterpret_cast<float4*>(qf2 + (size_t)(Rloc + r) * Uu + u0);
            dst[0] = make_float4(v[0], v[1], v[2], v[3]);
            dst[1] = make_float4(v[4], v[5], v[6], v[7]);
        } else {
            const int p = posLoc[r];
            if (p >= 0) {
                float* __restrict__ kb = kT + (size_t)(Rloc >> 9) * Uu * Tv;
                const int u4a = u0 >> 2;           // even quad index
                *reinterpret_cast<float4*>(kb + ((size_t)u4a       * Tv + p) * 4) =
                    make_float4(v[0], v[1], v[2], v[3]);
                *reinterpret_cast<float4*>(kb + ((size_t)(u4a + 1) * Tv + p) * 4) =
                    make_float4(v[4], v[5], v[6], v[7]);
            }
        }
    }
}

// ---------------------------------------------------------------------------
// Kernel B v2: attention over COMPACT keys. 8 query rows/block, 512 threads,
// 512 blocks.
//   score : u-SPLIT so all 512 threads are active (cnt~256 used to idle half):
//           group g=t>>8 computes u4-range [g*16,g*16+16) for jc=t&255;
//           g0 partials -> w, g1 partials -> pbuf (free until context).
//   softmax: wave wv -> row wv; combines the two u-half partials with the -2
//           factor; zero-pads w[e>=cnt] for the context float4 reads.
//   context: unchanged (group g owns a 4-aligned compact j-range; partials
//           combined via pbuf AFTER the softmax barrier).
// ---------------------------------------------------------------------------
__global__ __launch_bounds__(512) void attn_kernel(
    const float* __restrict__ qf2, const float* __restrict__ kT,
    const float* __restrict__ value,
    const int* __restrict__ mask,
    const float* __restrict__ scale,
    float* __restrict__ out)
{
    const int r0 = blockIdx.x * 8;            // first query row (0..4095)
    const int b  = r0 >> 9;
    const int t  = threadIdx.x;               // 0..511

    __shared__ float q2[8 * Uu];              // 4 KB
    __shared__ float s2[Uu];                  // 0.5 KB
    __shared__ int   jl[Tv];                  // 2 KB
    __shared__ float w[8 * Tv];               // 16 KB (u-half-0 partials -> softmax weights)
    __shared__ float pbuf[8 * Dd];            // 16 KB (u-half-1 partials, then context partials)
    __shared__ float inv8[8];
    __shared__ int   cntS;

    jl[t] = 0;
    if (t < 256)
        reinterpret_cast<float4*>(q2)[t] =
            reinterpret_cast<const float4*>(qf2 + (size_t)r0 * Uu)[t];
    else if (t < 384) s2[t - 256] = scale[t - 256];
    __syncthreads();
    if (t < 64) {                             // wave-0 ballot scan -> jl, cnt
        int base = 0;
#pragma unroll
        for (int c = 0; c < 8; ++c) {
            const int j = c * 64 + t;
            const int v = (mask[b * 512 + j] != 0);
            const unsigned long long bits = __ballot(v);
            const int pos = base + (int)__popcll(bits & ((1ull << t) - 1ull));
            if (v) jl[pos] = j;
            base += (int)__popcll(bits);
        }
        if (t == 0) cntS = base;
    }
    __syncthreads();

    const int cnt   = cntS;
    const int cntp4 = (cnt + 3) & ~3;

    // ---- scores: 2 u-half groups x 256 compact-j lanes, all threads active ----
    {
        const int g   = t >> 8;               // u-half
        const int jc0 = t & 255;
        const float4* __restrict__ kb4 =
            reinterpret_cast<const float4*>(kT) + (size_t)b * 32 * Tv + (size_t)g * 16 * Tv;
        float* __restrict__ wr = g ? pbuf : w;
        for (int jb = 0; jb < cnt; jb += 256) {   // cnt uniform -> uniform trip count
            const int jc = jb + jc0;
            if (jc < cnt) {
                float acc[8] = {0,0,0,0,0,0,0,0};
#pragma unroll 2
                for (int u4 = 0; u4 < 16; ++u4) {
                    const float4 kv = kb4[(size_t)u4 * Tv + jc];
                    const float4 sv = reinterpret_cast<const float4*>(s2)[g * 16 + u4];
#pragma unroll
                    for (int i = 0; i < 8; ++i) {
                        const float4 qv = *reinterpret_cast<const float4*>(
                            q2 + i * Uu + (g * 16 + u4) * 4);
                        float e0 = __builtin_amdgcn_exp2f(qv.x + kv.x);
                        float e1 = __builtin_amdgcn_exp2f(qv.y + kv.y);
                        float e2 = __builtin_amdgcn_exp2f(qv.z + kv.z);
                        float e3 = __builtin_amdgcn_exp2f(qv.w + kv.w);
                        acc[i] = fmaf(sv.x, __builtin_amdgcn_rcpf(e0 + 1.f), acc[i]);
                        acc[i] = fmaf(sv.y, __builtin_amdgcn_rcpf(e1 + 1.f), acc[i]);
                        acc[i] = fmaf(sv.z, __builtin_amdgcn_rcpf(e2 + 1.f), acc[i]);
                        acc[i] = fmaf(sv.w, __builtin_amdgcn_rcpf(e3 + 1.f), acc[i]);
                    }
                }
#pragma unroll
                for (int i = 0; i < 8; ++i) wr[i * Tv + jc] = acc[i];
            }
        }
    }
    __syncthreads();

    // ---- softmax over [0,cnt): wave wv -> row wv; combine u-half partials ----
    {
        const int wv = t >> 6, ln = t & 63;
        float* __restrict__ row        = w    + wv * Tv;
        const float* __restrict__ rowB = pbuf + wv * Tv;
        float vals[8];
        float m = -3e38f;
#pragma unroll
        for (int c = 0; c < 8; ++c) {
            const int e = ln + 64 * c;
            vals[c] = (e < cnt) ? -2.f * (row[e] + rowB[e]) : -3e38f;
            m = fmaxf(m, vals[c]);
        }
#pragma unroll
        for (int off = 32; off; off >>= 1) m = fmaxf(m, __shfl_xor(m, off, 64));
        float sum = 0.f;
#pragma unroll
        for (int c = 0; c < 8; ++c) {
            const int e = ln + 64 * c;
            if (e < cnt) {
                float ex = __builtin_amdgcn_exp2f((vals[c] - m) * LOG2E);
                row[e] = ex;
                sum += ex;
            } else {
                row[e] = 0.f;                  // pad for context float4 reads
            }
        }
#pragma unroll
        for (int off = 32; off; off >>= 1) sum += __shfl_xor(sum, off, 64);
        if (ln == 0) inv8[wv] = 1.0f / sum;
    }
    __syncthreads();

    // ---- context over compact rows: group g owns a 4-aligned range ----
    const int mid = ((cntp4 >> 1) + 3) & ~3;
    const int g  = t >> 8;                 // 0/1
    const int c  = t & 255;
    const int d0 = c * 2;
    const int jbeg = g ? mid : 0;
    const int jend = g ? cntp4 : mid;
    const float* __restrict__ vb = value + (size_t)b * Tv * Dd + d0;
    float ax[8], ay[8];
#pragma unroll
    for (int i = 0; i < 8; ++i) { ax[i] = 0.f; ay[i] = 0.f; }

    for (int jj = jbeg; jj < jend; jj += 4) {
        const int4 rows = *reinterpret_cast<const int4*>(jl + jj);
        const float2 v0 = *reinterpret_cast<const float2*>(vb + (size_t)rows.x * Dd);
        const float2 v1 = *reinterpret_cast<const float2*>(vb + (size_t)rows.y * Dd);
        const float2 v2 = *reinterpret_cast<const float2*>(vb + (size_t)rows.z * Dd);
        const float2 v3 = *reinterpret_cast<const float2*>(vb + (size_t)rows.w * Dd);
#pragma unroll
        for (int i = 0; i < 8; ++i) {
            const float4 wq = *reinterpret_cast<const float4*>(w + i * Tv + jj); // broadcast
            ax[i] = fmaf(wq.x, v0.x, ax[i]); ay[i] = fmaf(wq.x, v0.y, ay[i]);
            ax[i] = fmaf(wq.y, v1.x, ax[i]); ay[i] = fmaf(wq.y, v1.y, ay[i]);
            ax[i] = fmaf(wq.z, v2.x, ax[i]); ay[i] = fmaf(wq.z, v2.y, ay[i]);
            ax[i] = fmaf(wq.w, v3.x, ax[i]); ay[i] = fmaf(wq.w, v3.y, ay[i]);
        }
    }

    if (g == 1) {
#pragma unroll
        for (int i = 0; i < 8; ++i) {
            float2 p; p.x = ax[i]; p.y = ay[i];
            *reinterpret_cast<float2*>(pbuf + i * Dd + d0) = p;
        }
    }
    __syncthreads();
    if (g == 0) {
#pragma unroll
        for (int i = 0; i < 8; ++i) {
            const float inv = inv8[i];
            const float2 p1 = *reinterpret_cast<const float2*>(pbuf + i * Dd + d0);
            float2 o;
            o.x = (ax[i] + p1.x) * inv;
            o.y = (ay[i] + p1.y) * inv;
            *reinterpret_cast<float2*>(out + (size_t)(r0 + i) * Dd + d0) = o;
        }
    }
}

extern "C" void kernel_launch(void* const* d_in, const int* in_sizes, int n_in,
                              void* d_out, int out_size, void* d_ws, size_t ws_size,
                              hipStream_t stream)
{
    const float* query = (const float*)d_in[0];
    const float* key   = (const float*)d_in[1];
    const float* value = (const float*)d_in[2];
    const int*   mask  = (const int*)d_in[3];     // proven int32 (R2 bit-identical)
    const float* Wa    = (const float*)d_in[4];
    const float* Ua    = (const float*)d_in[5];
    const float* scale = (const float*)d_in[6];
    float* out = (float*)d_out;

    float* qf2 = (float*)d_ws;                    // [4096,128] = 2 MB (premult)
    float* kT  = qf2 + Bb * Tq * Uu;              // [8][32][512] float4 = 2 MB (compact, u4-interleaved)

    proj_kernel<<<(2 * Bb * Tq) / 16, 256, 0, stream>>>(query, key, Wa, Ua, mask, qf2, kT);
    attn_kernel<<<(Bb * Tq) / 8, 512, 0, stream>>>(qf2, kT, value, mask, scale, out);
}

// Round 2
// 153.539 us; speedup vs baseline: 1.1238x; 1.1238x over previous
//
#include <hip/hip_runtime.h>

// Problem constants (B=8, Tq=Tv=512, D=512, U=128)
constexpr int Bb = 8;
constexpr int Tq = 512;
constexpr int Tv = 512;
constexpr int Dd = 512;
constexpr int Uu = 128;
constexpr float C2LOG2E = 2.88539008177792681f;   // 2*log2(e)
constexpr float LOG2E   = 1.44269504088896341f;

// ---------------------------------------------------------------------------
// Kernel A v3: projections. 8 rows/block, 256 threads, 1024 blocks
// (4 blocks/CU -> 4 waves/SIMD, was 2). Each WAVE owns a d-quarter (128 d's);
// each thread accumulates all 8 rows x 2 u-cols (acc[8][2]); 4-way d-partials
// combined through LDS (aliased over x). Outputs premultiplied by 2*log2e.
// kT stays u4-interleaved compact: kT[b][u4][pos][comp].
// ---------------------------------------------------------------------------
__global__ __launch_bounds__(256, 4) void proj_kernel(
    const float* __restrict__ query,
    const float* __restrict__ key,
    const float* __restrict__ Wa,
    const float* __restrict__ Ua,
    const int* __restrict__ mask,
    float* __restrict__ qf2, float* __restrict__ kT)
{
    const int R    = blockIdx.x * 8;               // 0..8191
    const bool isQ = R < Bb * Tq;
    const float* __restrict__ src = isQ ? query : key;
    const float* __restrict__ W   = isQ ? Wa : Ua;
    const int Rloc = isQ ? R : R - Bb * Tq;        // 0..4095

    __shared__ float x[8 * Dd];                    // 16 KB; aliased as part[4][8][128]
    __shared__ int posLoc[8];
    const int t = threadIdx.x;

    {   // stage 8 rows: 1024 float4, coalesced, 4/thread
        const float4* __restrict__ s4 =
            reinterpret_cast<const float4*>(src + (size_t)Rloc * Dd);
        float4* x4 = reinterpret_cast<float4*>(x);
#pragma unroll
        for (int m = 0; m < 4; ++m) x4[t + 256 * m] = s4[t + 256 * m];
    }
    if (!isQ && t < 64) {                          // wave-0 ballot scan -> pos
        const int b  = Rloc >> 9;
        const int j0 = Rloc & 511;                 // 8-aligned
        int base = 0;
#pragma unroll
        for (int c = 0; c < 8; ++c) {
            const int j = c * 64 + t;
            const int v = (mask[b * 512 + j] != 0);
            const unsigned long long bits = __ballot(v);
            const int pos = base + (int)__popcll(bits & ((1ull << t) - 1ull));
            if (j >= j0 && j < j0 + 8) posLoc[j - j0] = v ? pos : -1;
            base += (int)__popcll(bits);
        }
    }
    __syncthreads();

    const int ub = t & 63;                         // u column pair (ub, ub+64)
    const int dq = t >> 6;                         // wave-owned d-quarter 0..3
    const float* __restrict__ Wq = W + (size_t)dq * 128 * Uu;
    const float* __restrict__ xq = x + dq * 128;

    float acc[8][2];
#pragma unroll
    for (int r = 0; r < 8; ++r) { acc[r][0] = 0.f; acc[r][1] = 0.f; }

#pragma unroll 2
    for (int d4 = 0; d4 < 32; ++d4) {
        const int d = d4 * 4;
        const float w0x = Wq[(d + 0) * Uu + ub], w1x = Wq[(d + 0) * Uu + ub + 64];
        const float w0y = Wq[(d + 1) * Uu + ub], w1y = Wq[(d + 1) * Uu + ub + 64];
        const float w0z = Wq[(d + 2) * Uu + ub], w1z = Wq[(d + 2) * Uu + ub + 64];
        const float w0w = Wq[(d + 3) * Uu + ub], w1w = Wq[(d + 3) * Uu + ub + 64];
#pragma unroll
        for (int r = 0; r < 8; ++r) {
            const float4 xv = *reinterpret_cast<const float4*>(xq + r * Dd + d); // LDS broadcast
            acc[r][0] = fmaf(xv.x, w0x, acc[r][0]);
            acc[r][0] = fmaf(xv.y, w0y, acc[r][0]);
            acc[r][0] = fmaf(xv.z, w0z, acc[r][0]);
            acc[r][0] = fmaf(xv.w, w0w, acc[r][0]);
            acc[r][1] = fmaf(xv.x, w1x, acc[r][1]);
            acc[r][1] = fmaf(xv.y, w1y, acc[r][1]);
            acc[r][1] = fmaf(xv.z, w1z, acc[r][1]);
            acc[r][1] = fmaf(xv.w, w1w, acc[r][1]);
        }
    }

    __syncthreads();                               // all waves done reading x
    {
        float* __restrict__ part = x;              // part[dq][r][u]
#pragma unroll
        for (int r = 0; r < 8; ++r) {              // stride-1 across lanes: conflict-free
            part[(dq * 8 + r) * 128 + ub]      = acc[r][0];
            part[(dq * 8 + r) * 128 + ub + 64] = acc[r][1];
        }
    }
    __syncthreads();

    // reduce 4 d-partials and store. thread -> row r = t>>5, u0 = (t&31)*4
    {
        const float* __restrict__ part = x;
        const int r  = t >> 5;
        const int u0 = (t & 31) * 4;
        const float4 p0 = *reinterpret_cast<const float4*>(part + (0 * 8 + r) * 128 + u0);
        const float4 p1 = *reinterpret_cast<const float4*>(part + (1 * 8 + r) * 128 + u0);
        const float4 p2 = *reinterpret_cast<const float4*>(part + (2 * 8 + r) * 128 + u0);
        const float4 p3 = *reinterpret_cast<const float4*>(part + (3 * 8 + r) * 128 + u0);
        float4 v;
        v.x = C2LOG2E * (p0.x + p1.x + p2.x + p3.x);
        v.y = C2LOG2E * (p0.y + p1.y + p2.y + p3.y);
        v.z = C2LOG2E * (p0.z + p1.z + p2.z + p3.z);
        v.w = C2LOG2E * (p0.w + p1.w + p2.w + p3.w);
        if (isQ) {
            *reinterpret_cast<float4*>(qf2 + (size_t)(Rloc + r) * Uu + u0) = v;
        } else {
            const int p = posLoc[r];
            if (p >= 0) {
                float* __restrict__ kb = kT + (size_t)(Rloc >> 9) * Uu * Tv;
                const int u4a = u0 >> 2;           // = t&31
                *reinterpret_cast<float4*>(kb + ((size_t)u4a * Tv + p) * 4) = v;
            }
        }
    }
}

// ---------------------------------------------------------------------------
// Kernel B v3: attention over COMPACT keys. 4 query rows/block, 512 threads,
// 1024 blocks -> 4 blocks/CU, 32 waves/CU (was 2 blocks, 16 waves).
// __launch_bounds__(512,8) caps VGPR at 64 for full occupancy.
// Bijective XCD swizzle: each XCD's L2 holds exactly one batch (kT 256KB +
// value 1MB + qf2 256KB < 4MB).
//   score : u-split, g=t>>8 computes u4-range [g*16,g*16+16) for jc=t&255;
//           g0 partials -> w, g1 -> pbuf.
//   softmax: waves 0..3 -> row wv; combines u-halves with the -2 factor;
//           zero-pads w[e>=cnt].
//   context: g owns a 4-aligned compact j-range; partials combined via pbuf.
// ---------------------------------------------------------------------------
__global__ __launch_bounds__(512, 8) void attn_kernel(
    const float* __restrict__ qf2, const float* __restrict__ kT,
    const float* __restrict__ value,
    const int* __restrict__ mask,
    const float* __restrict__ scale,
    float* __restrict__ out)
{
    // XCD-aware bijective swizzle (1024 % 8 == 0): XCD x <-> batch x
    const int bid = blockIdx.x;
    const int swz = (bid & 7) * 128 + (bid >> 3);
    const int r0 = swz * 4;                   // first query row (0..4092)
    const int b  = r0 >> 9;
    const int t  = threadIdx.x;               // 0..511

    __shared__ float q2[4 * Uu];              // 2 KB
    __shared__ float s2[Uu];                  // 0.5 KB
    __shared__ int   jl[Tv];                  // 2 KB
    __shared__ float w[4 * Tv];               // 8 KB (u-half-0 partials -> weights)
    __shared__ float pbuf[4 * Tv];            // 8 KB (u-half-1 partials, then context partials)
    __shared__ float inv4[4];
    __shared__ int   cntS;

    jl[t] = 0;
    if (t < 128)
        reinterpret_cast<float4*>(q2)[t] =
            reinterpret_cast<const float4*>(qf2 + (size_t)r0 * Uu)[t];
    else if (t < 256) s2[t - 128] = scale[t - 128];
    __syncthreads();
    if (t < 64) {                             // wave-0 ballot scan -> jl, cnt
        int base = 0;
#pragma unroll
        for (int c = 0; c < 8; ++c) {
            const int j = c * 64 + t;
            const int v = (mask[b * 512 + j] != 0);
            const unsigned long long bits = __ballot(v);
            const int pos = base + (int)__popcll(bits & ((1ull << t) - 1ull));
            if (v) jl[pos] = j;
            base += (int)__popcll(bits);
        }
        if (t == 0) cntS = base;
    }
    __syncthreads();

    const int cnt   = cntS;
    const int cntp4 = (cnt + 3) & ~3;

    // ---- scores: 2 u-half groups x 256 compact-j lanes ----
    {
        const int g   = t >> 8;               // u-half
        const int jc0 = t & 255;
        const float4* __restrict__ kb4 =
            reinterpret_cast<const float4*>(kT) + (size_t)b * 32 * Tv + (size_t)g * 16 * Tv;
        float* __restrict__ wr = g ? pbuf : w;
        for (int jb = 0; jb < cnt; jb += 256) {
            const int jc = jb + jc0;
            if (jc < cnt) {
                float acc[4] = {0, 0, 0, 0};
#pragma unroll 2
                for (int u4 = 0; u4 < 16; ++u4) {
                    const float4 kv = kb4[(size_t)u4 * Tv + jc];
                    const float4 sv = reinterpret_cast<const float4*>(s2)[g * 16 + u4];
#pragma unroll
                    for (int i = 0; i < 4; ++i) {
                        const float4 qv = *reinterpret_cast<const float4*>(
                            q2 + i * Uu + (g * 16 + u4) * 4);      // wave-uniform -> broadcast
                        float e0 = __builtin_amdgcn_exp2f(qv.x + kv.x);
                        float e1 = __builtin_amdgcn_exp2f(qv.y + kv.y);
                        float e2 = __builtin_amdgcn_exp2f(qv.z + kv.z);
                        float e3 = __builtin_amdgcn_exp2f(qv.w + kv.w);
                        acc[i] = fmaf(sv.x, __builtin_amdgcn_rcpf(e0 + 1.f), acc[i]);
                        acc[i] = fmaf(sv.y, __builtin_amdgcn_rcpf(e1 + 1.f), acc[i]);
                        acc[i] = fmaf(sv.z, __builtin_amdgcn_rcpf(e2 + 1.f), acc[i]);
                        acc[i] = fmaf(sv.w, __builtin_amdgcn_rcpf(e3 + 1.f), acc[i]);
                    }
                }
#pragma unroll
                for (int i = 0; i < 4; ++i) wr[i * Tv + jc] = acc[i];
            }
        }
    }
    __syncthreads();

    // ---- softmax over [0,cnt): waves 0..3 -> row wv ----
    {
        const int wv = t >> 6, ln = t & 63;
        if (wv < 4) {
            float* __restrict__ row        = w    + wv * Tv;
            const float* __restrict__ rowB = pbuf + wv * Tv;
            float vals[8];
            float m = -3e38f;
#pragma unroll
            for (int c = 0; c < 8; ++c) {
                const int e = ln + 64 * c;
                vals[c] = (e < cnt) ? -2.f * (row[e] + rowB[e]) : -3e38f;
                m = fmaxf(m, vals[c]);
            }
#pragma unroll
            for (int off = 32; off; off >>= 1) m = fmaxf(m, __shfl_xor(m, off, 64));
            float sum = 0.f;
#pragma unroll
            for (int c = 0; c < 8; ++c) {
                const int e = ln + 64 * c;
                if (e < cnt) {
                    float ex = __builtin_amdgcn_exp2f((vals[c] - m) * LOG2E);
                    row[e] = ex;
                    sum += ex;
                } else {
                    row[e] = 0.f;              // pad for context float4 reads
                }
            }
#pragma unroll
            for (int off = 32; off; off >>= 1) sum += __shfl_xor(sum, off, 64);
            if (ln == 0) inv4[wv] = 1.0f / sum;
        }
    }
    __syncthreads();

    // ---- context over compact rows: group g owns a 4-aligned range ----
    const int mid = ((cntp4 >> 1) + 3) & ~3;
    const int g  = t >> 8;                 // 0/1
    const int c  = t & 255;
    const int d0 = c * 2;
    const int jbeg = g ? mid : 0;
    const int jend = g ? cntp4 : mid;
    const float* __restrict__ vb = value + (size_t)b * Tv * Dd + d0;
    float ax[4], ay[4];
#pragma unroll
    for (int i = 0; i < 4; ++i) { ax[i] = 0.f; ay[i] = 0.f; }

    for (int jj = jbeg; jj < jend; jj += 4) {
        const int4 rows = *reinterpret_cast<const int4*>(jl + jj);
        const float2 v0 = *reinterpret_cast<const float2*>(vb + (size_t)rows.x * Dd);
        const float2 v1 = *reinterpret_cast<const float2*>(vb + (size_t)rows.y * Dd);
        const float2 v2 = *reinterpret_cast<const float2*>(vb + (size_t)rows.z * Dd);
        const float2 v3 = *reinterpret_cast<const float2*>(vb + (size_t)rows.w * Dd);
#pragma unroll
        for (int i = 0; i < 4; ++i) {
            const float4 wq = *reinterpret_cast<const float4*>(w + i * Tv + jj); // broadcast
            ax[i] = fmaf(wq.x, v0.x, ax[i]); ay[i] = fmaf(wq.x, v0.y, ay[i]);
            ax[i] = fmaf(wq.y, v1.x, ax[i]); ay[i] = fmaf(wq.y, v1.y, ay[i]);
            ax[i] = fmaf(wq.z, v2.x, ax[i]); ay[i] = fmaf(wq.z, v2.y, ay[i]);
            ax[i] = fmaf(wq.w, v3.x, ax[i]); ay[i] = fmaf(wq.w, v3.y, ay[i]);
        }
    }

    if (g == 1) {
#pragma unroll
        for (int i = 0; i < 4; ++i) {
            float2 p; p.x = ax[i]; p.y = ay[i];
            *reinterpret_cast<float2*>(pbuf + i * Dd + d0) = p;
        }
    }
    __syncthreads();
    if (g == 0) {
#pragma unroll
        for (int i = 0; i < 4; ++i) {
            const float inv = inv4[i];
            const float2 p1 = *reinterpret_cast<const float2*>(pbuf + i * Dd + d0);
            float2 o;
            o.x = (ax[i] + p1.x) * inv;
            o.y = (ay[i] + p1.y) * inv;
            *reinterpret_cast<float2*>(out + (size_t)(r0 + i) * Dd + d0) = o;
        }
    }
}

extern "C" void kernel_launch(void* const* d_in, const int* in_sizes, int n_in,
                              void* d_out, int out_size, void* d_ws, size_t ws_size,
                              hipStream_t stream)
{
    const float* query = (const float*)d_in[0];
    const float* key   = (const float*)d_in[1];
    const float* value = (const float*)d_in[2];
    const int*   mask  = (const int*)d_in[3];     // proven int32 (R2 bit-identical)
    const float* Wa    = (const float*)d_in[4];
    const float* Ua    = (const float*)d_in[5];
    const float* scale = (const float*)d_in[6];
    float* out = (float*)d_out;

    float* qf2 = (float*)d_ws;                    // [4096,128] = 2 MB (premult)
    float* kT  = qf2 + Bb * Tq * Uu;              // [8][32][512] float4 = 2 MB (compact, u4-interleaved)

    proj_kernel<<<(2 * Bb * Tq) / 8, 256, 0, stream>>>(query, key, Wa, Ua, mask, qf2, kT);
    attn_kernel<<<(Bb * Tq) / 4, 512, 0, stream>>>(qf2, kT, value, mask, scale, out);
}

// Round 3
// 151.162 us; speedup vs baseline: 1.1415x; 1.0157x over previous
//
#include <hip/hip_runtime.h>

// Problem constants (B=8, Tq=Tv=512, D=512, U=128)
constexpr int Bb = 8;
constexpr int Tq = 512;
constexpr int Tv = 512;
constexpr int Dd = 512;
constexpr int Uu = 128;
constexpr float C2LOG2E = 2.88539008177792681f;   // 2*log2(e)
constexpr float LOG2E   = 1.44269504088896341f;

// ---------------------------------------------------------------------------
// Kernel A v4: projections. 8 rows/block, 512 threads, 1024 blocks
// -> exactly 4 blocks/CU = 32 waves/CU (100% slots) for latency hiding of the
// L2-resident W stream. Each WAVE owns a d-EIGHTH (64 d's); each thread
// accumulates all 8 rows x 2 u-cols (acc[8][2]); 8-way d-partials combined
// through LDS (aliased over x).
// EPILOGUE CHANGE: outputs are now Eq = exp2(2log2e * q) (and Ek for keys),
// so the attention score loop needs only ONE transcendental per element:
//   tanh(q+k) = 1 - 2/(Eq*Ek + 1).
// kT stays u4-interleaved compact: kT[b][u4][pos][comp].
// ---------------------------------------------------------------------------
__global__ __launch_bounds__(512, 8) void proj_kernel(
    const float* __restrict__ query,
    const float* __restrict__ key,
    const float* __restrict__ Wa,
    const float* __restrict__ Ua,
    const int* __restrict__ mask,
    float* __restrict__ qf2, float* __restrict__ kT)
{
    const int R    = blockIdx.x * 8;               // 0..8191
    const bool isQ = R < Bb * Tq;
    const float* __restrict__ src = isQ ? query : key;
    const float* __restrict__ W   = isQ ? Wa : Ua;
    const int Rloc = isQ ? R : R - Bb * Tq;        // 0..4095

    __shared__ float smem[8 * 8 * 128];            // 32 KB: x[8][512] then part[8][8][128]
    __shared__ int posLoc[8];
    float* __restrict__ x = smem;
    const int t = threadIdx.x;

    {   // stage 8 rows: 1024 float4, coalesced, 2/thread
        const float4* __restrict__ s4 =
            reinterpret_cast<const float4*>(src + (size_t)Rloc * Dd);
        float4* x4 = reinterpret_cast<float4*>(x);
#pragma unroll
        for (int m = 0; m < 2; ++m) x4[t + 512 * m] = s4[t + 512 * m];
    }
    if (!isQ && t < 64) {                          // wave-0 ballot scan -> pos
        const int b  = Rloc >> 9;
        const int j0 = Rloc & 511;                 // 8-aligned
        int base = 0;
#pragma unroll
        for (int c = 0; c < 8; ++c) {
            const int j = c * 64 + t;
            const int v = (mask[b * 512 + j] != 0);
            const unsigned long long bits = __ballot(v);
            const int pos = base + (int)__popcll(bits & ((1ull << t) - 1ull));
            if (j >= j0 && j < j0 + 8) posLoc[j - j0] = v ? pos : -1;
            base += (int)__popcll(bits);
        }
    }
    __syncthreads();

    const int ub = t & 63;                         // u column pair (ub, ub+64)
    const int dq = t >> 6;                         // wave-owned d-eighth 0..7
    const float* __restrict__ Wq = W + (size_t)dq * 64 * Uu;
    const float* __restrict__ xq = x + dq * 64;

    float acc[8][2];
#pragma unroll
    for (int r = 0; r < 8; ++r) { acc[r][0] = 0.f; acc[r][1] = 0.f; }

#pragma unroll 2
    for (int d4 = 0; d4 < 16; ++d4) {
        const int d = d4 * 4;
        const float w0x = Wq[(d + 0) * Uu + ub], w1x = Wq[(d + 0) * Uu + ub + 64];
        const float w0y = Wq[(d + 1) * Uu + ub], w1y = Wq[(d + 1) * Uu + ub + 64];
        const float w0z = Wq[(d + 2) * Uu + ub], w1z = Wq[(d + 2) * Uu + ub + 64];
        const float w0w = Wq[(d + 3) * Uu + ub], w1w = Wq[(d + 3) * Uu + ub + 64];
#pragma unroll
        for (int r = 0; r < 8; ++r) {
            const float4 xv = *reinterpret_cast<const float4*>(xq + r * Dd + d); // LDS broadcast
            acc[r][0] = fmaf(xv.x, w0x, acc[r][0]);
            acc[r][0] = fmaf(xv.y, w0y, acc[r][0]);
            acc[r][0] = fmaf(xv.z, w0z, acc[r][0]);
            acc[r][0] = fmaf(xv.w, w0w, acc[r][0]);
            acc[r][1] = fmaf(xv.x, w1x, acc[r][1]);
            acc[r][1] = fmaf(xv.y, w1y, acc[r][1]);
            acc[r][1] = fmaf(xv.z, w1z, acc[r][1]);
            acc[r][1] = fmaf(xv.w, w1w, acc[r][1]);
        }
    }

    __syncthreads();                               // all waves done reading x
    {
        float* __restrict__ part = smem;           // part[dq][r][u]
#pragma unroll
        for (int r = 0; r < 8; ++r) {              // stride-1 across lanes: conflict-free
            part[(dq * 8 + r) * 128 + ub]      = acc[r][0];
            part[(dq * 8 + r) * 128 + ub + 64] = acc[r][1];
        }
    }
    __syncthreads();

    // reduce 8 d-partials, apply exp2(2log2e * .), store.
    // thread -> row r = t>>6, u0 = (t&63)*2
    {
        const float* __restrict__ part = smem;
        const int r  = t >> 6;
        const int u0 = (t & 63) * 2;
        float s0 = 0.f, s1 = 0.f;
#pragma unroll
        for (int p = 0; p < 8; ++p) {              // float2, 2-way bank alias: free
            const float2 pv = *reinterpret_cast<const float2*>(part + (p * 8 + r) * 128 + u0);
            s0 += pv.x;
            s1 += pv.y;
        }
        float2 e;
        e.x = __builtin_amdgcn_exp2f(C2LOG2E * s0);
        e.y = __builtin_amdgcn_exp2f(C2LOG2E * s1);
        if (isQ) {
            *reinterpret_cast<float2*>(qf2 + (size_t)(Rloc + r) * Uu + u0) = e;
        } else {
            const int p = posLoc[r];
            if (p >= 0) {
                float* __restrict__ kb = kT + (size_t)(Rloc >> 9) * Uu * Tv;
                const int u4 = u0 >> 2;            // quad index
                const int c  = u0 & 3;             // 0 or 2
                *reinterpret_cast<float2*>(kb + ((size_t)u4 * Tv + p) * 4 + c) = e;
            }
        }
    }
}

// ---------------------------------------------------------------------------
// Kernel B v4: attention over COMPACT exp-keys. 4 query rows/block,
// 512 threads, 1024 blocks, bijective XCD swizzle (batch <-> XCD L2).
//   score : ONE transcendental per element now:
//             term = rcp(fma(Eq, Ek, 1))   [= sigmoid-style 1/(e^{2(q+k)}+1)]
//           u-split g=t>>8 over u4-range [g*16,g*16+16) for jc=t&255;
//           g0 partials -> w, g1 -> pbuf.
//   softmax: waves 0..3 -> row wv; score = -2*(accA+accB) (+const, cancels);
//           zero-pads w[e>=cnt].
//   context: g owns a 4-aligned compact j-range; partials combined via pbuf.
// ---------------------------------------------------------------------------
__global__ __launch_bounds__(512, 8) void attn_kernel(
    const float* __restrict__ qf2, const float* __restrict__ kT,
    const float* __restrict__ value,
    const int* __restrict__ mask,
    const float* __restrict__ scale,
    float* __restrict__ out)
{
    // XCD-aware bijective swizzle (1024 % 8 == 0): XCD x <-> batch x
    const int bid = blockIdx.x;
    const int swz = (bid & 7) * 128 + (bid >> 3);
    const int r0 = swz * 4;                   // first query row (0..4092)
    const int b  = r0 >> 9;
    const int t  = threadIdx.x;               // 0..511

    __shared__ float q2[4 * Uu];              // 2 KB (Eq)
    __shared__ float s2[Uu];                  // 0.5 KB
    __shared__ int   jl[Tv];                  // 2 KB
    __shared__ float w[4 * Tv];               // 8 KB (u-half-0 partials -> weights)
    __shared__ float pbuf[4 * Tv];            // 8 KB (u-half-1 partials, then context partials)
    __shared__ float inv4[4];
    __shared__ int   cntS;

    jl[t] = 0;
    if (t < 128)
        reinterpret_cast<float4*>(q2)[t] =
            reinterpret_cast<const float4*>(qf2 + (size_t)r0 * Uu)[t];
    else if (t < 256) s2[t - 128] = scale[t - 128];
    __syncthreads();
    if (t < 64) {                             // wave-0 ballot scan -> jl, cnt
        int base = 0;
#pragma unroll
        for (int c = 0; c < 8; ++c) {
            const int j = c * 64 + t;
            const int v = (mask[b * 512 + j] != 0);
            const unsigned long long bits = __ballot(v);
            const int pos = base + (int)__popcll(bits & ((1ull << t) - 1ull));
            if (v) jl[pos] = j;
            base += (int)__popcll(bits);
        }
        if (t == 0) cntS = base;
    }
    __syncthreads();

    const int cnt   = cntS;
    const int cntp4 = (cnt + 3) & ~3;

    // ---- scores: 2 u-half groups x 256 compact-j lanes, 1 trans/element ----
    {
        const int g   = t >> 8;               // u-half
        const int jc0 = t & 255;
        const float4* __restrict__ kb4 =
            reinterpret_cast<const float4*>(kT) + (size_t)b * 32 * Tv + (size_t)g * 16 * Tv;
        float* __restrict__ wr = g ? pbuf : w;
        for (int jb = 0; jb < cnt; jb += 256) {
            const int jc = jb + jc0;
            if (jc < cnt) {
                float acc[4] = {0, 0, 0, 0};
#pragma unroll 2
                for (int u4 = 0; u4 < 16; ++u4) {
                    const float4 kv = kb4[(size_t)u4 * Tv + jc];
                    const float4 sv = reinterpret_cast<const float4*>(s2)[g * 16 + u4];
#pragma unroll
                    for (int i = 0; i < 4; ++i) {
                        const float4 qv = *reinterpret_cast<const float4*>(
                            q2 + i * Uu + (g * 16 + u4) * 4);      // wave-uniform -> broadcast
                        const float p0 = fmaf(qv.x, kv.x, 1.f);
                        const float p1 = fmaf(qv.y, kv.y, 1.f);
                        const float p2 = fmaf(qv.z, kv.z, 1.f);
                        const float p3 = fmaf(qv.w, kv.w, 1.f);
                        acc[i] = fmaf(sv.x, __builtin_amdgcn_rcpf(p0), acc[i]);
                        acc[i] = fmaf(sv.y, __builtin_amdgcn_rcpf(p1), acc[i]);
                        acc[i] = fmaf(sv.z, __builtin_amdgcn_rcpf(p2), acc[i]);
                        acc[i] = fmaf(sv.w, __builtin_amdgcn_rcpf(p3), acc[i]);
                    }
                }
#pragma unroll
                for (int i = 0; i < 4; ++i) wr[i * Tv + jc] = acc[i];
            }
        }
    }
    __syncthreads();

    // ---- softmax over [0,cnt): waves 0..3 -> row wv ----
    {
        const int wv = t >> 6, ln = t & 63;
        if (wv < 4) {
            float* __restrict__ row        = w    + wv * Tv;
            const float* __restrict__ rowB = pbuf + wv * Tv;
            float vals[8];
            float m = -3e38f;
#pragma unroll
            for (int c = 0; c < 8; ++c) {
                const int e = ln + 64 * c;
                vals[c] = (e < cnt) ? -2.f * (row[e] + rowB[e]) : -3e38f;
                m = fmaxf(m, vals[c]);
            }
#pragma unroll
            for (int off = 32; off; off >>= 1) m = fmaxf(m, __shfl_xor(m, off, 64));
            float sum = 0.f;
#pragma unroll
            for (int c = 0; c < 8; ++c) {
                const int e = ln + 64 * c;
                if (e < cnt) {
                    float ex = __builtin_amdgcn_exp2f((vals[c] - m) * LOG2E);
                    row[e] = ex;
                    sum += ex;
                } else {
                    row[e] = 0.f;              // pad for context float4 reads
                }
            }
#pragma unroll
            for (int off = 32; off; off >>= 1) sum += __shfl_xor(sum, off, 64);
            if (ln == 0) inv4[wv] = 1.0f / sum;
        }
    }
    __syncthreads();

    // ---- context over compact rows: group g owns a 4-aligned range ----
    const int mid = ((cntp4 >> 1) + 3) & ~3;
    const int g  = t >> 8;                 // 0/1
    const int c  = t & 255;
    const int d0 = c * 2;
    const int jbeg = g ? mid : 0;
    const int jend = g ? cntp4 : mid;
    const float* __restrict__ vb = value + (size_t)b * Tv * Dd + d0;
    float ax[4], ay[4];
#pragma unroll
    for (int i = 0; i < 4; ++i) { ax[i] = 0.f; ay[i] = 0.f; }

    for (int jj = jbeg; jj < jend; jj += 4) {
        const int4 rows = *reinterpret_cast<const int4*>(jl + jj);
        const float2 v0 = *reinterpret_cast<const float2*>(vb + (size_t)rows.x * Dd);
        const float2 v1 = *reinterpret_cast<const float2*>(vb + (size_t)rows.y * Dd);
        const float2 v2 = *reinterpret_cast<const float2*>(vb + (size_t)rows.z * Dd);
        const float2 v3 = *reinterpret_cast<const float2*>(vb + (size_t)rows.w * Dd);
#pragma unroll
        for (int i = 0; i < 4; ++i) {
            const float4 wq = *reinterpret_cast<const float4*>(w + i * Tv + jj); // broadcast
            ax[i] = fmaf(wq.x, v0.x, ax[i]); ay[i] = fmaf(wq.x, v0.y, ay[i]);
            ax[i] = fmaf(wq.y, v1.x, ax[i]); ay[i] = fmaf(wq.y, v1.y, ay[i]);
            ax[i] = fmaf(wq.z, v2.x, ax[i]); ay[i] = fmaf(wq.z, v2.y, ay[i]);
            ax[i] = fmaf(wq.w, v3.x, ax[i]); ay[i] = fmaf(wq.w, v3.y, ay[i]);
        }
    }

    if (g == 1) {
#pragma unroll
        for (int i = 0; i < 4; ++i) {
            float2 p; p.x = ax[i]; p.y = ay[i];
            *reinterpret_cast<float2*>(pbuf + i * Dd + d0) = p;
        }
    }
    __syncthreads();
    if (g == 0) {
#pragma unroll
        for (int i = 0; i < 4; ++i) {
            const float inv = inv4[i];
            const float2 p1 = *reinterpret_cast<const float2*>(pbuf + i * Dd + d0);
            float2 o;
            o.x = (ax[i] + p1.x) * inv;
            o.y = (ay[i] + p1.y) * inv;
            *reinterpret_cast<float2*>(out + (size_t)(r0 + i) * Dd + d0) = o;
        }
    }
}

extern "C" void kernel_launch(void* const* d_in, const int* in_sizes, int n_in,
                              void* d_out, int out_size, void* d_ws, size_t ws_size,
                              hipStream_t stream)
{
    const float* query = (const float*)d_in[0];
    const float* key   = (const float*)d_in[1];
    const float* value = (const float*)d_in[2];
    const int*   mask  = (const int*)d_in[3];     // proven int32 (R2 bit-identical)
    const float* Wa    = (const float*)d_in[4];
    const float* Ua    = (const float*)d_in[5];
    const float* scale = (const float*)d_in[6];
    float* out = (float*)d_out;

    float* qf2 = (float*)d_ws;                    // [4096,128] = 2 MB (Eq = exp2(2log2e*q))
    float* kT  = qf2 + Bb * Tq * Uu;              // [8][32][512] float4 = 2 MB (Ek, compact, u4-interleaved)

    proj_kernel<<<(2 * Bb * Tq) / 8, 512, 0, stream>>>(query, key, Wa, Ua, mask, qf2, kT);
    attn_kernel<<<(Bb * Tq) / 4, 512, 0, stream>>>(qf2, kT, value, mask, scale, out);
}

// Round 4
// 150.943 us; speedup vs baseline: 1.1431x; 1.0015x over previous
//
#include <hip/hip_runtime.h>

// Problem constants (B=8, Tq=Tv=512, D=512, U=128)
constexpr int Bb = 8;
constexpr int Tq = 512;
constexpr int Tv = 512;
constexpr int Dd = 512;
constexpr int Uu = 128;
constexpr float C2LOG2E = 2.88539008177792681f;   // 2*log2(e)

// ---------------------------------------------------------------------------
// Kernel A v5: projections. 8 rows/block, 512 threads, 1024 blocks
// (4 blocks/CU = 32 waves/CU). Wave owns a d-eighth; acc[8][2]/thread;
// 8-way d-partials combined through LDS. Outputs Eq = exp2(2log2e*q) /
// Ek likewise, so attention needs ONE rcp-class op per element.
// NEW: the j0==0 key-block exports the mask scan (jl_g[b][*], cnt_g[b])
// so attn no longer runs a serial wave-0 ballot scan.
// ---------------------------------------------------------------------------
__global__ __launch_bounds__(512, 8) void proj_kernel(
    const float* __restrict__ query,
    const float* __restrict__ key,
    const float* __restrict__ Wa,
    const float* __restrict__ Ua,
    const int* __restrict__ mask,
    float* __restrict__ qf2, float* __restrict__ kT,
    int* __restrict__ jl_g, int* __restrict__ cnt_g)
{
    const int R    = blockIdx.x * 8;               // 0..8191
    const bool isQ = R < Bb * Tq;
    const float* __restrict__ src = isQ ? query : key;
    const float* __restrict__ W   = isQ ? Wa : Ua;
    const int Rloc = isQ ? R : R - Bb * Tq;        // 0..4095

    __shared__ float smem[8 * 8 * 128];            // 32 KB: x[8][512] then part[8][8][128]
    __shared__ int posLoc[8];
    float* __restrict__ x = smem;
    const int t = threadIdx.x;

    {   // stage 8 rows: 1024 float4, coalesced, 2/thread
        const float4* __restrict__ s4 =
            reinterpret_cast<const float4*>(src + (size_t)Rloc * Dd);
        float4* x4 = reinterpret_cast<float4*>(x);
#pragma unroll
        for (int m = 0; m < 2; ++m) x4[t + 512 * m] = s4[t + 512 * m];
    }
    if (!isQ && t < 64) {                          // wave-0 ballot scan -> pos
        const int b  = Rloc >> 9;
        const int j0 = Rloc & 511;                 // 8-aligned
        const bool writer = (j0 == 0);             // one block per batch exports
        int base = 0;
#pragma unroll
        for (int c = 0; c < 8; ++c) {
            const int j = c * 64 + t;
            const int v = (mask[b * 512 + j] != 0);
            const unsigned long long bits = __ballot(v);
            const int pos = base + (int)__popcll(bits & ((1ull << t) - 1ull));
            if (j >= j0 && j < j0 + 8) posLoc[j - j0] = v ? pos : -1;
            if (writer && v) jl_g[b * 512 + pos] = j;
            base += (int)__popcll(bits);
        }
        if (writer && t == 0) cnt_g[b] = base;
    }
    __syncthreads();

    const int ub = t & 63;                         // u column pair (ub, ub+64)
    const int dq = t >> 6;                         // wave-owned d-eighth 0..7
    const float* __restrict__ Wq = W + (size_t)dq * 64 * Uu;
    const float* __restrict__ xq = x + dq * 64;

    float acc[8][2];
#pragma unroll
    for (int r = 0; r < 8; ++r) { acc[r][0] = 0.f; acc[r][1] = 0.f; }

#pragma unroll 2
    for (int d4 = 0; d4 < 16; ++d4) {
        const int d = d4 * 4;
        const float w0x = Wq[(d + 0) * Uu + ub], w1x = Wq[(d + 0) * Uu + ub + 64];
        const float w0y = Wq[(d + 1) * Uu + ub], w1y = Wq[(d + 1) * Uu + ub + 64];
        const float w0z = Wq[(d + 2) * Uu + ub], w1z = Wq[(d + 2) * Uu + ub + 64];
        const float w0w = Wq[(d + 3) * Uu + ub], w1w = Wq[(d + 3) * Uu + ub + 64];
#pragma unroll
        for (int r = 0; r < 8; ++r) {
            const float4 xv = *reinterpret_cast<const float4*>(xq + r * Dd + d); // LDS broadcast
            acc[r][0] = fmaf(xv.x, w0x, acc[r][0]);
            acc[r][0] = fmaf(xv.y, w0y, acc[r][0]);
            acc[r][0] = fmaf(xv.z, w0z, acc[r][0]);
            acc[r][0] = fmaf(xv.w, w0w, acc[r][0]);
            acc[r][1] = fmaf(xv.x, w1x, acc[r][1]);
            acc[r][1] = fmaf(xv.y, w1y, acc[r][1]);
            acc[r][1] = fmaf(xv.z, w1z, acc[r][1]);
            acc[r][1] = fmaf(xv.w, w1w, acc[r][1]);
        }
    }

    __syncthreads();                               // all waves done reading x
    {
        float* __restrict__ part = smem;           // part[dq][r][u]
#pragma unroll
        for (int r = 0; r < 8; ++r) {              // stride-1 across lanes: conflict-free
            part[(dq * 8 + r) * 128 + ub]      = acc[r][0];
            part[(dq * 8 + r) * 128 + ub + 64] = acc[r][1];
        }
    }
    __syncthreads();

    // reduce 8 d-partials, apply exp2(2log2e * .), store.
    // thread -> row r = t>>6, u0 = (t&63)*2
    {
        const float* __restrict__ part = smem;
        const int r  = t >> 6;
        const int u0 = (t & 63) * 2;
        float s0 = 0.f, s1 = 0.f;
#pragma unroll
        for (int p = 0; p < 8; ++p) {              // float2, 2-way bank alias: free
            const float2 pv = *reinterpret_cast<const float2*>(part + (p * 8 + r) * 128 + u0);
            s0 += pv.x;
            s1 += pv.y;
        }
        float2 e;
        e.x = __builtin_amdgcn_exp2f(C2LOG2E * s0);
        e.y = __builtin_amdgcn_exp2f(C2LOG2E * s1);
        if (isQ) {
            *reinterpret_cast<float2*>(qf2 + (size_t)(Rloc + r) * Uu + u0) = e;
        } else {
            const int p = posLoc[r];
            if (p >= 0) {
                float* __restrict__ kb = kT + (size_t)(Rloc >> 9) * Uu * Tv;
                const int u4 = u0 >> 2;            // quad index
                const int c  = u0 & 3;             // 0 or 2
                *reinterpret_cast<float2*>(kb + ((size_t)u4 * Tv + p) * 4 + c) = e;
            }
        }
    }
}

// ---------------------------------------------------------------------------
// Kernel B v5: attention over COMPACT exp-keys. 4 query rows/block,
// 512 threads, 1024 blocks, bijective XCD swizzle (batch <-> XCD L2).
//   prologue: jl/cnt loaded from workspace (scan hoisted to proj).
//   score  : PAIRED reciprocals -- 1/pa,1/pb from one rcp(pa*pb) (+3 mul);
//            valid since p>=1 and pa*pb<=~1e19. u-split g=t>>8; unroll 4.
//   softmax: NO max pass (|score| <= sum|scale| ~ 10.2 -> exp in [1e-9,3e4],
//            overflow impossible; constant shift cancels in softmax).
//            All 8 waves: wave wv -> row wv>>1, half wv&1; sums8[] in LDS.
//   context: 1-deep software pipeline on the jl->value gather chain;
//            g owns a 4-aligned compact j-range; partials via pbuf.
// ---------------------------------------------------------------------------
__global__ __launch_bounds__(512, 8) void attn_kernel(
    const float* __restrict__ qf2, const float* __restrict__ kT,
    const float* __restrict__ value,
    const int* __restrict__ jl_g, const int* __restrict__ cnt_g,
    const float* __restrict__ scale,
    float* __restrict__ out)
{
    // XCD-aware bijective swizzle (1024 % 8 == 0): XCD x <-> batch x
    const int bid = blockIdx.x;
    const int swz = (bid & 7) * 128 + (bid >> 3);
    const int r0 = swz * 4;                   // first query row (0..4092)
    const int b  = r0 >> 9;
    const int t  = threadIdx.x;               // 0..511

    __shared__ float q2[4 * Uu];              // 2 KB (Eq)
    __shared__ float s2[Uu];                  // 0.5 KB
    __shared__ int   jl[Tv];                  // 2 KB
    __shared__ float w[4 * Tv];               // 8 KB (u-half-0 partials -> weights)
    __shared__ float pbuf[4 * Tv];            // 8 KB (u-half-1 partials, then context partials)
    __shared__ float sums8[8];                // per (row, half) exp-sums
    const int cnt = cnt_g[b];

    if (t < 128)
        reinterpret_cast<float4*>(q2)[t] =
            reinterpret_cast<const float4*>(qf2 + (size_t)r0 * Uu)[t];
    else if (t < 160)
        reinterpret_cast<float4*>(s2)[t - 128] =
            reinterpret_cast<const float4*>(scale)[t - 128];
    jl[t] = (t < cnt) ? jl_g[b * 512 + t] : 0;
    __syncthreads();

    const int cntp4 = (cnt + 3) & ~3;

    // ---- scores: 2 u-half groups x 256 compact-j lanes, paired rcp ----
    {
        const int g   = t >> 8;               // u-half
        const int jc0 = t & 255;
        const float4* __restrict__ kb4 =
            reinterpret_cast<const float4*>(kT) + (size_t)b * 32 * Tv + (size_t)g * 16 * Tv;
        float* __restrict__ wr = g ? pbuf : w;
        for (int jb = 0; jb < cnt; jb += 256) {
            const int jc = jb + jc0;
            if (jc < cnt) {
                float acc[4] = {0, 0, 0, 0};
#pragma unroll 4
                for (int u4 = 0; u4 < 16; ++u4) {
                    const float4 kv = kb4[(size_t)u4 * Tv + jc];
                    const float4 sv = reinterpret_cast<const float4*>(s2)[g * 16 + u4];
#pragma unroll
                    for (int i = 0; i < 4; ++i) {
                        const float4 qv = *reinterpret_cast<const float4*>(
                            q2 + i * Uu + (g * 16 + u4) * 4);      // wave-uniform -> broadcast
                        const float pa = fmaf(qv.x, kv.x, 1.f);
                        const float pb = fmaf(qv.y, kv.y, 1.f);
                        const float pc = fmaf(qv.z, kv.z, 1.f);
                        const float pd = fmaf(qv.w, kv.w, 1.f);
                        const float ra = __builtin_amdgcn_rcpf(pa * pb);
                        const float rc = __builtin_amdgcn_rcpf(pc * pd);
                        acc[i] = fmaf(sv.x, ra * pb, acc[i]);
                        acc[i] = fmaf(sv.y, ra * pa, acc[i]);
                        acc[i] = fmaf(sv.z, rc * pd, acc[i]);
                        acc[i] = fmaf(sv.w, rc * pc, acc[i]);
                    }
                }
#pragma unroll
                for (int i = 0; i < 4; ++i) wr[i * Tv + jc] = acc[i];
            }
        }
    }
    __syncthreads();

    // ---- softmax, no max pass: wave wv -> row wv>>1, half wv&1 ----
    {
        const int wv = t >> 6, ln = t & 63;
        const int i = wv >> 1, h = wv & 1;
        float* __restrict__ row        = w    + i * Tv;
        const float* __restrict__ rowB = pbuf + i * Tv;
        float sum = 0.f;
#pragma unroll
        for (int c = 0; c < 4; ++c) {
            const int e = ln + 64 * (h * 4 + c);
            if (e < cnt) {
                // score - const = -2*(rA+rB); bounded by ~|sum scale| -> safe
                const float ex = __builtin_amdgcn_exp2f(-C2LOG2E * (row[e] + rowB[e]));
                row[e] = ex;
                sum += ex;
            } else {
                row[e] = 0.f;                  // pad for context float4 reads
            }
        }
#pragma unroll
        for (int off = 32; off; off >>= 1) sum += __shfl_xor(sum, off, 64);
        if (ln == 0) sums8[wv] = sum;          // wv = 2*i + h
    }
    __syncthreads();

    // ---- context over compact rows: group g owns a 4-aligned range ----
    const int mid = ((cntp4 >> 1) + 3) & ~3;
    const int g  = t >> 8;                 // 0/1
    const int c  = t & 255;
    const int d0 = c * 2;
    const int jbeg = g ? mid : 0;
    const int jend = g ? cntp4 : mid;
    const float* __restrict__ vb = value + (size_t)b * Tv * Dd + d0;
    float ax[4], ay[4];
#pragma unroll
    for (int i = 0; i < 4; ++i) { ax[i] = 0.f; ay[i] = 0.f; }

    if (jbeg < jend) {                     // 1-deep software pipeline
        int jj = jbeg;
        int4 rows = *reinterpret_cast<const int4*>(jl + jj);
        float2 v0 = *reinterpret_cast<const float2*>(vb + (size_t)rows.x * Dd);
        float2 v1 = *reinterpret_cast<const float2*>(vb + (size_t)rows.y * Dd);
        float2 v2 = *reinterpret_cast<const float2*>(vb + (size_t)rows.z * Dd);
        float2 v3 = *reinterpret_cast<const float2*>(vb + (size_t)rows.w * Dd);
        for (; jj + 4 < jend; jj += 4) {
            const int4 rowsN = *reinterpret_cast<const int4*>(jl + jj + 4);
            const float2 n0 = *reinterpret_cast<const float2*>(vb + (size_t)rowsN.x * Dd);
            const float2 n1 = *reinterpret_cast<const float2*>(vb + (size_t)rowsN.y * Dd);
            const float2 n2 = *reinterpret_cast<const float2*>(vb + (size_t)rowsN.z * Dd);
            const float2 n3 = *reinterpret_cast<const float2*>(vb + (size_t)rowsN.w * Dd);
#pragma unroll
            for (int i = 0; i < 4; ++i) {
                const float4 wq = *reinterpret_cast<const float4*>(w + i * Tv + jj);
                ax[i] = fmaf(wq.x, v0.x, ax[i]); ay[i] = fmaf(wq.x, v0.y, ay[i]);
                ax[i] = fmaf(wq.y, v1.x, ax[i]); ay[i] = fmaf(wq.y, v1.y, ay[i]);
                ax[i] = fmaf(wq.z, v2.x, ax[i]); ay[i] = fmaf(wq.z, v2.y, ay[i]);
                ax[i] = fmaf(wq.w, v3.x, ax[i]); ay[i] = fmaf(wq.w, v3.y, ay[i]);
            }
            v0 = n0; v1 = n1; v2 = n2; v3 = n3;
        }
#pragma unroll
        for (int i = 0; i < 4; ++i) {          // drain last group
            const float4 wq = *reinterpret_cast<const float4*>(w + i * Tv + jj);
            ax[i] = fmaf(wq.x, v0.x, ax[i]); ay[i] = fmaf(wq.x, v0.y, ay[i]);
            ax[i] = fmaf(wq.y, v1.x, ax[i]); ay[i] = fmaf(wq.y, v1.y, ay[i]);
            ax[i] = fmaf(wq.z, v2.x, ax[i]); ay[i] = fmaf(wq.z, v2.y, ay[i]);
            ax[i] = fmaf(wq.w, v3.x, ax[i]); ay[i] = fmaf(wq.w, v3.y, ay[i]);
        }
    }

    if (g == 1) {
#pragma unroll
        for (int i = 0; i < 4; ++i) {
            float2 p; p.x = ax[i]; p.y = ay[i];
            *reinterpret_cast<float2*>(pbuf + i * Dd + d0) = p;
        }
    }
    __syncthreads();
    if (g == 0) {
#pragma unroll
        for (int i = 0; i < 4; ++i) {
            const float inv = 1.0f / (sums8[2 * i] + sums8[2 * i + 1]);
            const float2 p1 = *reinterpret_cast<const float2*>(pbuf + i * Dd + d0);
            float2 o;
            o.x = (ax[i] + p1.x) * inv;
            o.y = (ay[i] + p1.y) * inv;
            *reinterpret_cast<float2*>(out + (size_t)(r0 + i) * Dd + d0) = o;
        }
    }
}

extern "C" void kernel_launch(void* const* d_in, const int* in_sizes, int n_in,
                              void* d_out, int out_size, void* d_ws, size_t ws_size,
                              hipStream_t stream)
{
    const float* query = (const float*)d_in[0];
    const float* key   = (const float*)d_in[1];
    const float* value = (const float*)d_in[2];
    const int*   mask  = (const int*)d_in[3];     // proven int32 (R2 bit-identical)
    const float* Wa    = (const float*)d_in[4];
    const float* Ua    = (const float*)d_in[5];
    const float* scale = (const float*)d_in[6];
    float* out = (float*)d_out;

    float* qf2 = (float*)d_ws;                    // [4096,128] = 2 MB (Eq)
    float* kT  = qf2 + Bb * Tq * Uu;              // [8][32][512] float4 = 2 MB (Ek, compact)
    int*   jl_g  = (int*)(kT + Bb * Uu * Tv);     // [8][512] compact index lists
    int*   cnt_g = jl_g + Bb * Tv;                // [8]

    proj_kernel<<<(2 * Bb * Tq) / 8, 512, 0, stream>>>(query, key, Wa, Ua, mask,
                                                       qf2, kT, jl_g, cnt_g);
    attn_kernel<<<(Bb * Tq) / 4, 512, 0, stream>>>(qf2, kT, value, jl_g, cnt_g,
                                                   scale, out);
}